// Round 16
// baseline (156.167 us; speedup 1.0000x reference)
//
#include <hip/hip_runtime.h>
#include <stdint.h>

// Square-attack schedule collapse for B=1, C=3, H=224, EPS=0.05, N_QUERIES=5000.
//
// R15 calibration: fill 40.1 + slack ~6 = 46 us floor; R13 (2 kernels) = 66.1
// => build+gap+resolve ~= 20 us. R15's redundant per-block build = 63.7 us
// kernel (98x redundant RNG) -- reverted. R16: ONE plain kernel, producer/
// consumer via spin flags: blocks 0..23 build the 24 (seg,c) tables (R13-
// verified code), publish with __threadfence + agent release-store of MAGIC
// flags (d_ws 0xAA-poisoned every launch => flags start != MAGIC); all 294
// blocks prefetch x, compute init-sign inline, spin (thread0 polls, bounded),
// then resolve via agent-scope loads (sc0/sc1 -- consumer XCD L2 holds stale
// poison lines for gtab, must bypass). Co-residency: 294 blocks x 8 waves =
// 2352 << 8192 wave slots => no deadlock; bounded spin => no hang ever.
//
// RNG: JAX threefry2x32, jax_threefry_partitionable=True (verified exact):
//   fold_in(key, d)          = tf(key, (0, d))
//   split(k)                 = k1 = tf(k,(0,0)), k2 = tf(k,(0,1))
//   random_bits(key,32,n)[i] = X0 ^ X1 of tf(key, (0, i))

#define HH 224
#define NQ 5000
#define NPIX (HH * HH)      // 50176 = 98 * 512
#define EPSF 0.05f
#define MAGIC 0x5EED0000u

__device__ __forceinline__ void tf2x32(uint32_t k0, uint32_t k1,
                                       uint32_t x0, uint32_t x1,
                                       uint32_t& o0, uint32_t& o1) {
  uint32_t ks2 = k0 ^ k1 ^ 0x1BD11BDAu;
  x0 += k0; x1 += k1;
#define TFR(r) { x0 += x1; x1 = (x1 << (r)) | (x1 >> (32 - (r))); x1 ^= x0; }
  TFR(13) TFR(15) TFR(26) TFR(6)
  x0 += k1;  x1 += ks2 + 1u;
  TFR(17) TFR(29) TFR(16) TFR(24)
  x0 += ks2; x1 += k0 + 2u;
  TFR(13) TFR(15) TFR(26) TFR(6)
  x0 += k0;  x1 += k1 + 3u;
  TFR(17) TFR(29) TFR(16) TFR(24)
  x0 += k1;  x1 += ks2 + 4u;
  TFR(13) TFR(15) TFR(26) TFR(6)
  x0 += ks2; x1 += k0 + 5u;
#undef TFR
  o0 = x0; o1 = x1;
}

__device__ __forceinline__ int sign_from_bits(uint32_t bits) {
  uint32_t mant = bits >> 9;
  return (mant > 0x400000u) ? 1 : ((mant < 0x400000u) ? -1 : 0);
}

__device__ __forceinline__ float u01_from_bits(uint32_t bits) {
  return __uint_as_float(0x3f800000u | (bits >> 9)) - 1.0f;
}

__constant__ int SEG_LO_C[8] = {0, 11, 51, 201, 501, 1001, 2001, 4001};
__constant__ int SEG_HI_C[8] = {10, 50, 200, 500, 1000, 2000, 4000, 4999};
__constant__ int SEG_SZ_C[8] = {200, 142, 100, 71, 50, 35, 25, 18};

// ONE kernel: 294 blocks x 512.
// Producer phase (blocks 0..23 only): build (seg,c) range-max table, publish.
// Consumer phase (all blocks): spin on 24 flags, resolve 512 pixels each.
__global__ __launch_bounds__(512) void spin_fused(const float* __restrict__ x,
                                                  float* __restrict__ out,
                                                  uint16_t* __restrict__ gtab,
                                                  uint32_t* __restrict__ flags) {
  __shared__ uint32_t bins[224];
  __shared__ uint16_t tab[8 * 224];
  __shared__ int ready;
  int blk = blockIdx.x;
  int tid = threadIdx.x;

  if (blk < 24) {   // ---- producer: R13-verified per-(seg,c) build ----
    int seg = blk / 3, c = blk % 3;
    int s = SEG_SZ_C[seg];
    if (tid < 224) bins[tid] = 0;
    __syncthreads();
    for (int t = SEG_LO_C[seg] + tid; t <= SEG_HI_C[seg]; t += 512) {
      uint32_t f0, f1;
      tf2x32(0u, 1u, 0u, (uint32_t)(t + 1), f0, f1);      // k = fold_in(base, t+1)
      uint32_t a0, a1, b0, b1;
      tf2x32(f0, f1, 0u, 0u, a0, a1);                     // k1 = tf(k, (0,0))
      tf2x32(f0, f1, 0u, 1u, b0, b1);                     // k2 = tf(k, (0,1))
      uint32_t u0, u1;
      tf2x32(a0, a1, 0u, 0u, u0, u1);                     // scalar uniform bits
      int vh = (int)floorf(u01_from_bits(u0 ^ u1) * (float)(HH - s));
      uint32_t c0, c1;
      tf2x32(b0, b1, 0u, (uint32_t)c, c0, c1);            // this channel's sign
      int g = sign_from_bits(c0 ^ c1);
      if (g) atomicMax(&bins[vh], (((uint32_t)(t + 1)) << 1) | (uint32_t)(g > 0));
    }
    __syncthreads();
    if (tid < 224) tab[tid] = (uint16_t)bins[tid];        // tree level 0
    __syncthreads();
    for (int k = 1; k < 8; ++k) {
      int w = 1 << (k - 1);
      if (tid < 224) {
        uint16_t a = tab[(k - 1) * 224 + tid];
        uint16_t b = (tid + w < 224) ? tab[(k - 1) * 224 + tid + w] : (uint16_t)0;
        tab[k * 224 + tid] = (a > b) ? a : b;
      }
      __syncthreads();
    }
    const uint32_t* t32 = (const uint32_t*)tab;
    uint32_t* g32 = (uint32_t*)(gtab + (seg * 3 + c) * 1792);   // 896 u32
    for (int i = tid; i < 896; i += 512) g32[i] = t32[i];
    __threadfence();                                      // drain to device scope
    __syncthreads();
    if (tid == 0)
      __hip_atomic_store(&flags[blk], MAGIC + (uint32_t)blk,
                         __ATOMIC_RELEASE, __HIP_MEMORY_SCOPE_AGENT);
  }

  // ---- consumer phase (every block) ----
  int c = blk / 98;                         // NPIX = 98*512 exactly
  int p = (blk - c * 98) * 512 + tid;
  int gid = c * NPIX + p;
  float xv = x[gid];                        // prefetch under the spin

  // init stripe sign inline: k0 = fold_in(base,0); bits = X0^X1 of tf(k0,(0,c*224+pj))
  int pj = p % HH;
  int isg;
  {
    uint32_t g0, g1, o0, o1;
    tf2x32(0u, 1u, 0u, 0u, g0, g1);
    tf2x32(g0, g1, 0u, (uint32_t)(c * HH + pj), o0, o1);
    isg = sign_from_bits(o0 ^ o1);
  }

  if (tid == 0) {                           // bounded spin; proceed regardless
    int good = 0;
    for (int it = 0; it < (1 << 22) && good < 24; ++it) {
      good = 0;
      for (int i = 0; i < 24; ++i)
        good += (__hip_atomic_load(&flags[i], __ATOMIC_ACQUIRE,
                                   __HIP_MEMORY_SCOPE_AGENT) == MAGIC + (uint32_t)i);
      if (good < 24) __builtin_amdgcn_s_sleep(8);
    }
    ready = 1;
  }
  __syncthreads();
  (void)ready;

  int pi = p / HH;
  int m = min(pi, pj), M = max(pi, pj);
  const uint32_t* gt32 = (const uint32_t*)gtab;

  const int SEG_S[8] = {200, 142, 100, 71, 50, 35, 25, 18};
  uint32_t best = 0;
#pragma unroll
  for (int seg = 0; seg < 8; ++seg) {
    const int s = SEG_S[seg];
    int lo = max(0, M - s + 1);
    int hi = min(m, 223 - s);
    bool ok = (lo <= hi);
    int len = ok ? (hi - lo + 1) : 1;
    int k = 31 - __clz(len);
    int o2 = hi + 1 - (1 << k);             // >= lo >= 0 when ok; == hi when !ok
    int e1 = c * 1792 + seg * 5376 + k * 224 + lo;
    int e2 = c * 1792 + seg * 5376 + k * 224 + o2;
    // agent-scope loads (sc0/sc1): bypass this XCD's stale poison lines
    uint32_t w1 = __hip_atomic_load(&gt32[e1 >> 1], __ATOMIC_RELAXED,
                                    __HIP_MEMORY_SCOPE_AGENT);
    uint32_t w2 = __hip_atomic_load(&gt32[e2 >> 1], __ATOMIC_RELAXED,
                                    __HIP_MEMORY_SCOPE_AGENT);
    uint32_t v1 = (w1 >> ((e1 & 1) * 16)) & 0xFFFFu;
    uint32_t v2 = (w2 >> ((e2 & 1) * 16)) & 0xFFFFu;
    uint32_t v = max(v1, v2);
    best = max(best, ok ? v : 0u);
  }

  int sg = best ? ((best & 1u) ? 1 : -1) : isg;

  out[gid] = (sg > 0) ? fminf(xv + EPSF, 1.0f)
           : (sg < 0) ? fmaxf(xv - EPSF, 0.0f)
                      : fminf(fmaxf(xv, 0.0f), 1.0f);
}

extern "C" void kernel_launch(void* const* d_in, const int* in_sizes, int n_in,
                              void* d_out, int out_size, void* d_ws, size_t ws_size,
                              hipStream_t stream) {
  const float* x = (const float*)d_in[0];
  float* out = (float*)d_out;
  uint16_t* gtab = (uint16_t*)d_ws;                          // 86016 B
  uint32_t* flags = (uint32_t*)((char*)d_ws + 86016);        // 24 u32, 4-aligned

  spin_fused<<<294, 512, 0, stream>>>(x, out, gtab, flags);
}

// Round 17
// 69.202 us; speedup vs baseline: 2.2567x; 2.2567x over previous
//
#include <hip/hip_runtime.h>
#include <stdint.h>

// Square-attack schedule collapse for B=1, C=3, H=224, EPS=0.05, N_QUERIES=5000.
//
// R16: spin producer/consumer = 136us kernel, VALUBusy 1.1% -- cross-XCD
// agent-scope coherence is ~100us-class on MI355X. Reverted.
// R17 = R13 (best, 66.1us) + BISECT PROBE: resolve launched TWICE (it is
// idempotent -- pure function of gtab/gisign/x). dur(R17)-dur(R13) = resolve
// + gap, the quantity hidden below the 40us poison-fill rows in the top-5
// counter table. Decides whether R18 optimizes build or resolve.
//
// RNG: JAX threefry2x32, jax_threefry_partitionable=True (verified exact):
//   fold_in(key, d)          = tf(key, (0, d))
//   split(k)                 = k1 = tf(k,(0,0)), k2 = tf(k,(0,1))
//   random_bits(key,32,n)[i] = X0 ^ X1 of tf(key, (0, i))

#define HH 224
#define NQ 5000
#define NPIX (HH * HH)      // 50176 = 196 * 256
#define EPSF 0.05f

__device__ __forceinline__ void tf2x32(uint32_t k0, uint32_t k1,
                                       uint32_t x0, uint32_t x1,
                                       uint32_t& o0, uint32_t& o1) {
  uint32_t ks2 = k0 ^ k1 ^ 0x1BD11BDAu;
  x0 += k0; x1 += k1;
#define TFR(r) { x0 += x1; x1 = (x1 << (r)) | (x1 >> (32 - (r))); x1 ^= x0; }
  TFR(13) TFR(15) TFR(26) TFR(6)
  x0 += k1;  x1 += ks2 + 1u;
  TFR(17) TFR(29) TFR(16) TFR(24)
  x0 += ks2; x1 += k0 + 2u;
  TFR(13) TFR(15) TFR(26) TFR(6)
  x0 += k0;  x1 += k1 + 3u;
  TFR(17) TFR(29) TFR(16) TFR(24)
  x0 += k1;  x1 += ks2 + 4u;
  TFR(13) TFR(15) TFR(26) TFR(6)
  x0 += ks2; x1 += k0 + 5u;
#undef TFR
  o0 = x0; o1 = x1;
}

__device__ __forceinline__ int sign_from_bits(uint32_t bits) {
  uint32_t mant = bits >> 9;
  return (mant > 0x400000u) ? 1 : ((mant < 0x400000u) ? -1 : 0);
}

__device__ __forceinline__ float u01_from_bits(uint32_t bits) {
  return __uint_as_float(0x3f800000u | (bits >> 9)) - 1.0f;
}

__constant__ int SEG_LO_C[8] = {0, 11, 51, 201, 501, 1001, 2001, 4001};
__constant__ int SEG_HI_C[8] = {10, 50, 200, 500, 1000, 2000, 4000, 4999};
__constant__ int SEG_SZ_C[8] = {200, 142, 100, 71, 50, 35, 25, 18};

// --- Kernel 1: 25 blocks x 512. Blocks 0..23 = (seg, c): recompute segment
// RNG, bin by vh (atomicMax of ((t+1)<<1 | sign>0)), build 8-level range-max
// tree, write 3584 B. Block 24: 672 init stripe signs. (R11/R13-verified.)
__global__ __launch_bounds__(512) void build_kernel(uint16_t* __restrict__ gtab,
                                                    int8_t* __restrict__ gisign) {
  int blk = blockIdx.x;
  int tid = threadIdx.x;

  if (blk == 24) {   // init signs: k0 = fold_in(base,0); bits[n] = X0^X1 of tf(k0,(0,n))
    uint32_t g0, g1;
    tf2x32(0u, 1u, 0u, 0u, g0, g1);
    for (int i = tid; i < 3 * HH; i += 512) {
      uint32_t o0, o1;
      tf2x32(g0, g1, 0u, (uint32_t)i, o0, o1);
      gisign[i] = (int8_t)sign_from_bits(o0 ^ o1);
    }
    return;
  }

  int seg = blk / 3, c = blk % 3;
  int s = SEG_SZ_C[seg];
  __shared__ uint32_t bins[224];
  __shared__ uint16_t tab[8 * 224];
  if (tid < 224) bins[tid] = 0;
  __syncthreads();

  for (int t = SEG_LO_C[seg] + tid; t <= SEG_HI_C[seg]; t += 512) {
    uint32_t f0, f1;
    tf2x32(0u, 1u, 0u, (uint32_t)(t + 1), f0, f1);      // k = fold_in(base, t+1)
    uint32_t a0, a1, b0, b1;
    tf2x32(f0, f1, 0u, 0u, a0, a1);                     // k1 = tf(k, (0,0))
    tf2x32(f0, f1, 0u, 1u, b0, b1);                     // k2 = tf(k, (0,1))
    uint32_t u0, u1;
    tf2x32(a0, a1, 0u, 0u, u0, u1);                     // scalar uniform bits
    int vh = (int)floorf(u01_from_bits(u0 ^ u1) * (float)(HH - s));
    uint32_t c0, c1;
    tf2x32(b0, b1, 0u, (uint32_t)c, c0, c1);            // this channel's sign bits
    int g = sign_from_bits(c0 ^ c1);
    if (g) atomicMax(&bins[vh], (((uint32_t)(t + 1)) << 1) | (uint32_t)(g > 0));
  }
  __syncthreads();

  if (tid < 224) tab[tid] = (uint16_t)bins[tid];        // tree level 0
  __syncthreads();
  for (int k = 1; k < 8; ++k) {
    int w = 1 << (k - 1);
    if (tid < 224) {
      uint16_t a = tab[(k - 1) * 224 + tid];
      uint16_t b = (tid + w < 224) ? tab[(k - 1) * 224 + tid + w] : (uint16_t)0;
      tab[k * 224 + tid] = (a > b) ? a : b;
    }
    __syncthreads();
  }

  const uint32_t* t32 = (const uint32_t*)tab;
  uint32_t* g32 = (uint32_t*)(gtab + (seg * 3 + c) * 1792);   // 1792 u16 = 896 u32
  for (int i = tid; i < 896; i += 512) g32[i] = t32[i];
}

// --- Kernel 2: one thread per (pixel, channel); 16 independent u16 global
// loads (8 segs x 2, L2-resident table); emit rail value. No LDS.
// IDEMPOTENT: launched twice in R17 as a timing bisect probe.
__global__ __launch_bounds__(256) void resolve_kernel(const uint16_t* __restrict__ gtab,
                                                      const int8_t* __restrict__ isign,
                                                      const float* __restrict__ x,
                                                      float* __restrict__ out) {
  int c = blockIdx.y;
  int p = blockIdx.x * 256 + threadIdx.x;   // 0..50175
  int pi = p / HH, pj = p % HH;
  int m = min(pi, pj), M = max(pi, pj);

  const uint16_t* tc = gtab + c * 1792;     // [seg][c][k][v]: + seg*5376 + k*224 + v

  const int SEG_S[8] = {200, 142, 100, 71, 50, 35, 25, 18};
  uint32_t best = 0;
#pragma unroll
  for (int seg = 0; seg < 8; ++seg) {
    const int s = SEG_S[seg];
    int lo = max(0, M - s + 1);
    int hi = min(m, 223 - s);
    bool ok = (lo <= hi);
    int len = ok ? (hi - lo + 1) : 1;
    int k = 31 - __clz(len);
    int o2 = hi + 1 - (1 << k);             // >= lo >= 0 when ok; == hi when !ok
    int b = seg * 5376 + k * 224;
    uint32_t v = max((uint32_t)tc[b + lo], (uint32_t)tc[b + o2]);
    best = max(best, ok ? v : 0u);
  }

  int sg = best ? ((best & 1u) ? 1 : -1) : (int)isign[c * HH + pj];

  int idx = c * NPIX + p;
  float xv = x[idx];
  out[idx] = (sg > 0) ? fminf(xv + EPSF, 1.0f)
           : (sg < 0) ? fmaxf(xv - EPSF, 0.0f)
                      : fminf(fmaxf(xv, 0.0f), 1.0f);
}

extern "C" void kernel_launch(void* const* d_in, const int* in_sizes, int n_in,
                              void* d_out, int out_size, void* d_ws, size_t ws_size,
                              hipStream_t stream) {
  const float* x = (const float*)d_in[0];
  float* out = (float*)d_out;
  uint16_t* gtab = (uint16_t*)d_ws;                          // 86016 B, 16-aligned
  int8_t* gisign = (int8_t*)d_ws + 86016;                    // 672 B

  build_kernel<<<25, 512, 0, stream>>>(gtab, gisign);
  dim3 rgrid(NPIX / 256, 3);
  resolve_kernel<<<rgrid, 256, 0, stream>>>(gtab, gisign, x, out);
  // Bisect probe: identical second resolve (idempotent). dur - 66.1 = resolve+gap.
  resolve_kernel<<<rgrid, 256, 0, stream>>>(gtab, gisign, x, out);
}